// Round 22
// baseline (213.585 us; speedup 1.0000x reference)
//
#include <hip/hip_runtime.h>

#define NCH 1024          // LSTM chunks (divisible by 4)
#define CL 48             // steps per chunk
#define WM 16             // warm-up steps (validated: absmax unchanged)
// dual-stream, red 1.33, 10 waves/CU offered — R20 best-known config (205.7 us).
// R21 lesson: [s][j][n] al layout fragments LSTM stores (WRITE +12MB) — net loss.

typedef _Float16 half8 __attribute__((ext_vector_type(8)));  // 8 f16 in 4 VGPRs
typedef float f32x4 __attribute__((ext_vector_type(4)));

#define ROWB 256          // bytes per LDS row (128 f16)
#define BUFB 17408        // 68 rows * 256 B
#define ALH_OFF 131072    // ushort offset of f16 al inside ws (weights live below)

__device__ __forceinline__ int swz(int srow, int b){ return srow*ROWB + (b ^ ((srow&7)<<4)); }

__device__ __forceinline__ unsigned short f2h_bits(float x){
  _Float16 h = (_Float16)x;
  return __builtin_bit_cast(unsigned short, h);
}

__device__ __forceinline__ float rcp_(float x){ return __builtin_amdgcn_rcpf(x); }
__device__ __forceinline__ float tanh_(float z){ return 1.f - 2.f*rcp_(1.f + __expf(2.f*z)); }

// ---------------- kernel 0: pack conv weights as f16 MFMA B-fragments ----------------
__global__ void pack_frags(const float* __restrict__ W1, const float* __restrict__ W2,
                           const float* __restrict__ W3, unsigned short* __restrict__ ws)
{
  int tid = blockIdx.x*256 + threadIdx.x;
  if (tid >= 174*512) return;
  int f = tid >> 9, e = tid & 511, l = e >> 3, j = e & 7;
  int d, ks, nt, I, O; const float* W;
  if (f < 42)      { int x = f;     int st = x/7;  nt = x%7; d = st/2; ks = st%2; I = 50;  O = 100; W = W1; }
  else if (f < 126){ int x = f-42;  int st = x/7;  nt = x%7; d = st/4; ks = st%4; I = 100; O = 100; W = W2; }
  else             { int x = f-126; int st = x/4;  nt = x%4; d = st/4; ks = st%4; I = 100; O = 50;  W = W3; }
  int k = ks*32 + ((l>>4)<<3) + j;
  int o = nt*16 + (l&15);
  float v = (k < I && o < O) ? W[((o*I + k)*3 + d)*3 + 1] : 0.f;
  ws[tid] = f2h_bits(v);
}

// ---------------- kernel 1: LSTM scan, dual-stream, 2 waves/WG (R20 config) ----------
template<bool F16>
__global__ __launch_bounds__(128,3) void lstm_scan2(
    const float* __restrict__ X, const float* __restrict__ Wih,
    const float* __restrict__ Whh, const float* __restrict__ bih,
    const float* __restrict__ bhh, float* __restrict__ al32,
    unsigned short* __restrict__ al16)
{
  const int l = threadIdx.x & 63;
  const int wv = threadIdx.x >> 6;
  const int blk = blockIdx.x;
  const int p4 = blk/5, w = blk - p4*5;
  const int q = l/6, j = l - q*6;
  const bool active = (q < 10);
  const int n = w*10 + (active ? q : 0);
  const int sbase = active ? q*6 : 0;

  const int c0 = p4*4 + 2*wv;           // this wave: chunks c0, c0+1
  const int sAb = c0*CL, sBb = sAb + CL;
  const int sALast = sAb + CL - 1, sBLast = sBb + CL - 1;

  float wi[4][12], wh[4][6], bb[4];
  #pragma unroll
  for (int g=0; g<4; ++g){
    const int r = g*6 + j;
    const float4 w0 = *(const float4*)(Wih + r*12);
    const float4 w1 = *(const float4*)(Wih + r*12 + 4);
    const float4 w2 = *(const float4*)(Wih + r*12 + 8);
    wi[g][0]=w0.x; wi[g][1]=w0.y; wi[g][2]=w0.z; wi[g][3]=w0.w;
    wi[g][4]=w1.x; wi[g][5]=w1.y; wi[g][6]=w1.z; wi[g][7]=w1.w;
    wi[g][8]=w2.x; wi[g][9]=w2.y; wi[g][10]=w2.z; wi[g][11]=w2.w;
    const float2 h0 = *(const float2*)(Whh + r*6);
    const float2 h1 = *(const float2*)(Whh + r*6 + 2);
    const float2 h2 = *(const float2*)(Whh + r*6 + 4);
    wh[g][0]=h0.x; wh[g][1]=h0.y; wh[g][2]=h1.x;
    wh[g][3]=h1.y; wh[g][4]=h2.x; wh[g][5]=h2.y;
    bb[g] = bih[r] + bhh[r];
  }

  float hA[6], hB[6], cA = 0.f, cB = 0.f;
  #pragma unroll
  for (int k=0;k<6;++k){ hA[k]=0.f; hB[k]=0.f; }

  const int sA0 = (c0==0) ? 0 : (sAb - WM);
  const int sB0 = sBb - WM;
  float4 xA0,xA1,xA2, xB0,xB1,xB2;
  { const float4* pa = (const float4*)(X + (size_t)sA0*600 + n*12); xA0=pa[0]; xA1=pa[1]; xA2=pa[2]; }
  { const float4* pb = (const float4*)(X + (size_t)sB0*600 + n*12); xB0=pb[0]; xB1=pb[1]; xB2=pb[2]; }

  auto step = [&](const float4& x0, const float4& x1, const float4& x2,
                  float* h, float& c) -> float {
    const float xr[12] = {x0.x,x0.y,x0.z,x0.w, x1.x,x1.y,x1.z,x1.w, x2.x,x2.y,x2.z,x2.w};
    float a0=bb[0], a1=bb[1], a2=bb[2], a3=bb[3];
    #pragma unroll
    for (int k=0;k<12;++k){ a0+=wi[0][k]*xr[k]; a1+=wi[1][k]*xr[k];
                            a2+=wi[2][k]*xr[k]; a3+=wi[3][k]*xr[k]; }
    #pragma unroll
    for (int k=0;k<6;++k){ a0+=wh[0][k]*h[k]; a1+=wh[1][k]*h[k];
                           a2+=wh[2][k]*h[k]; a3+=wh[3][k]*h[k]; }
    const float gi = rcp_(1.f + __expf(-a0));
    const float gf = rcp_(1.f + __expf(-a1));
    const float gg = 2.f*rcp_(1.f + __expf(-(a2+a2))) - 1.f;
    const float go = rcp_(1.f + __expf(-a3));
    c = gf*c + gi*gg;
    return tanh_(go * tanh_(c));
  };

  for (int i = -WM; i < CL; ++i){
    const int sA = sAb + i, sB = sBb + i;
    const bool doA = (sA >= 0);           // false only for c0==0 warm-up iters (uniform)
    float4 yA0,yA1,yA2, yB0,yB1,yB2;
    { const int sn = (sB < sBLast) ? sB+1 : sBLast;
      const float4* xq = (const float4*)(X + (size_t)sn*600 + n*12);
      yB0=xq[0]; yB1=xq[1]; yB2=xq[2]; }
    if (doA){
      const int sn = (sA < sALast) ? sA+1 : sALast;
      const float4* xq = (const float4*)(X + (size_t)sn*600 + n*12);
      yA0=xq[0]; yA1=xq[1]; yA2=xq[2];
    }

    float hnA = 0.f;
    if (doA) hnA = step(xA0,xA1,xA2, hA, cA);
    const float hnB = step(xB0,xB1,xB2, hB, cB);

    if (active && i >= 0){
      const size_t oA = (size_t)sA*300 + n*6 + j;
      const size_t oB = (size_t)sB*300 + n*6 + j;
      if (F16){ al16[oA] = f2h_bits(hnA); al16[oB] = f2h_bits(hnB); }
      else    { al32[oA] = hnA;           al32[oB] = hnB; }
    }
    #pragma unroll
    for (int k=0;k<6;++k){
      hA[k] = __shfl(hnA, sbase + k, 64);
      hB[k] = __shfl(hnB, sbase + k, 64);
    }
    if (doA){ xA0=yA0; xA1=yA1; xA2=yA2; }
    xB0=yB0; xB1=yB1; xB2=yB2;
  }
}

// ---------------- kernel 2: f16 MFMA conv x3, lean FUSED into L3 epilogue ------------
template<int KS, int NTT, int NTG, bool LAST>
__device__ __forceinline__ void conv_layer2(
    char* lds, int inOff, int outOff, const unsigned short* __restrict__ wsU,
    int fbase, int ntOff, const float* __restrict__ bias, int O, int m0, int lane)
{
  f32x4 acc[2][NTG];
  #pragma unroll
  for (int m=0;m<2;m++)
    #pragma unroll
    for (int n=0;n<NTG;n++) acc[m][n] = (f32x4){0.f,0.f,0.f,0.f};

  const int ar = m0 + (lane & 15);
  const int abyte_g = (lane>>4)<<4;
  const int laneb = lane << 3;

  half8 a0c = *(const half8*)(lds + inOff + swz(ar, abyte_g));
  half8 a1c = *(const half8*)(lds + inOff + swz(ar + 16, abyte_g));
  half8 bc[NTG];
  {
    const unsigned short* p0 = wsU + (size_t)(fbase + ntOff)*512 + laneb;
    #pragma unroll
    for (int n=0;n<NTG;n++) bc[n] = *(const half8*)(p0 + n*512);
  }

  #pragma unroll
  for (int st=0; st<3*KS; ++st){
    half8 a0n, a1n, bn[NTG];
    if (st+1 < 3*KS){
      const int dn = (st+1)/KS, ksn = (st+1)%KS;
      a0n = *(const half8*)(lds + inOff + swz(ar + dn, ksn*64 + abyte_g));
      a1n = *(const half8*)(lds + inOff + swz(ar + 16 + dn, ksn*64 + abyte_g));
      const unsigned short* pn = wsU + (size_t)(fbase + (st+1)*NTT + ntOff)*512 + laneb;
      #pragma unroll
      for (int n=0;n<NTG;n++) bn[n] = *(const half8*)(pn + n*512);
    }
    #pragma unroll
    for (int n=0;n<NTG;n++){
      acc[0][n] = __builtin_amdgcn_mfma_f32_16x16x32_f16(a0c, bc[n], acc[0][n], 0, 0, 0);
      acc[1][n] = __builtin_amdgcn_mfma_f32_16x16x32_f16(a1c, bc[n], acc[1][n], 0, 0, 0);
    }
    if (st+1 < 3*KS){
      a0c = a0n; a1c = a1n;
      #pragma unroll
      for (int n=0;n<NTG;n++) bc[n] = bn[n];
    }
  }

  const int colBase = lane & 15;
  #pragma unroll
  for (int m=0;m<2;m++){
    const int rbase = m0 + m*16 + ((lane>>4)<<2);
    #pragma unroll
    for (int n=0;n<NTG;n++){
      const int col = (ntOff + n)*16 + colBase;
      if (col < O){
        const float b = bias[col];
        #pragma unroll
        for (int r=0;r<4;r++){
          const int crow = rbase + r;
          const int p8 = crow & 7;
          if (p8 >= 1 && p8 <= 6){
            const float v = fmaxf(acc[m][n][r] + b, 0.f);
            const int srow = crow + 1;
            if (LAST) *(float*)(lds + outOff + swz(srow, col*4)) = v;
            else      *(unsigned short*)(lds + outOff + swz(srow, col*2)) = f2h_bits(v);
          }
        }
      }
    }
  }
}

// L3 with fused lean (proven R14): relu(conv3)+b3 in regs; quad pairs via lane^16;
// lean = 18 reg-FMA + 6 shfl_xor + 3 float2 global stores.
template<int KS, int NTT, int NTG>
__device__ __forceinline__ void conv_layer3_fused(
    char* lds, int inOff, const unsigned short* __restrict__ wsU,
    int fbase, int ntOff, const float* __restrict__ b3,
    const float* __restrict__ Wl, const float* __restrict__ bl,
    float* __restrict__ io, size_t base, int m0, int lane)
{
  f32x4 acc[2][NTG];
  #pragma unroll
  for (int m=0;m<2;m++)
    #pragma unroll
    for (int n=0;n<NTG;n++) acc[m][n] = (f32x4){0.f,0.f,0.f,0.f};

  const int ar = m0 + (lane & 15);
  const int abyte_g = (lane>>4)<<4;
  const int laneb = lane << 3;

  half8 a0c = *(const half8*)(lds + inOff + swz(ar, abyte_g));
  half8 a1c = *(const half8*)(lds + inOff + swz(ar + 16, abyte_g));
  half8 bc[NTG];
  {
    const unsigned short* p0 = wsU + (size_t)(fbase + ntOff)*512 + laneb;
    #pragma unroll
    for (int n=0;n<NTG;n++) bc[n] = *(const half8*)(p0 + n*512);
  }

  #pragma unroll
  for (int st=0; st<3*KS; ++st){
    half8 a0n, a1n, bn[NTG];
    if (st+1 < 3*KS){
      const int dn = (st+1)/KS, ksn = (st+1)%KS;
      a0n = *(const half8*)(lds + inOff + swz(ar + dn, ksn*64 + abyte_g));
      a1n = *(const half8*)(lds + inOff + swz(ar + 16 + dn, ksn*64 + abyte_g));
      const unsigned short* pn = wsU + (size_t)(fbase + (st+1)*NTT + ntOff)*512 + laneb;
      #pragma unroll
      for (int n=0;n<NTG;n++) bn[n] = *(const half8*)(pn + n*512);
    }
    #pragma unroll
    for (int n=0;n<NTG;n++){
      acc[0][n] = __builtin_amdgcn_mfma_f32_16x16x32_f16(a0c, bc[n], acc[0][n], 0, 0, 0);
      acc[1][n] = __builtin_amdgcn_mfma_f32_16x16x32_f16(a1c, bc[n], acc[1][n], 0, 0, 0);
    }
    if (st+1 < 3*KS){
      a0c = a0n; a1c = a1n;
      #pragma unroll
      for (int n=0;n<NTG;n++) bc[n] = bn[n];
    }
  }

  const int colBase = lane & 15;
  const int qg = lane >> 4;
  const bool hiHalf = (qg & 1);
  #pragma unroll
  for (int m=0;m<2;m++){
    const int sIdx = (m0 + m*16 + qg*4) >> 3;
    #pragma unroll
    for (int n=0;n<NTG;n++){
      const int col = (ntOff + n)*16 + colBase;
      const bool valid = (col < 50);
      const float b = valid ? b3[col] : 0.f;
      float vv[4];
      #pragma unroll
      for (int r=0;r<4;r++) vv[r] = fmaxf(acc[m][n][r] + b, 0.f);
      float tot[6];
      #pragma unroll
      for (int j=0;j<6;j++){
        float pj;
        if (!hiHalf) pj = Wl[j*6+0]*vv[1] + Wl[j*6+1]*vv[2] + Wl[j*6+2]*vv[3];
        else         pj = Wl[j*6+3]*vv[0] + Wl[j*6+4]*vv[1] + Wl[j*6+5]*vv[2];
        tot[j] = pj + __shfl_xor(pj, 16, 64);
      }
      if (valid && !hiHalf){
        float* dst = io + base + (size_t)sIdx*300 + col*6;
        float2 p0 = {tot[0]+bl[0], tot[1]+bl[1]};
        float2 p1 = {tot[2]+bl[2], tot[3]+bl[3]};
        float2 p2 = {tot[4]+bl[4], tot[5]+bl[5]};
        *(float2*)(dst+0) = p0;
        *(float2*)(dst+2) = p1;
        *(float2*)(dst+4) = p2;
      }
    }
  }
}

template<bool ALH>
__global__ __launch_bounds__(256,4) void conv_mfma_kernel(
    float* __restrict__ io, const unsigned short* __restrict__ alh,
    const unsigned short* __restrict__ wsU,
    const float* __restrict__ b1, const float* __restrict__ b2, const float* __restrict__ b3,
    const float* __restrict__ Wl, const float* __restrict__ bl)
{
  __shared__ __align__(16) char lds[2*BUFB];
  const int t = threadIdx.x;
  const int lane = t & 63, w = t >> 6;
  const int mg = w >> 1, ng = w & 1;
  const int m0 = mg*32;
  const size_t base = (size_t)blockIdx.x * 2400;

  // Zero BOTH buffers fully (R6 lesson: LDS NaN in the K-pad is laundered to wrong
  // finite values by fmaxf(NaN,0)=0 -> silent corruption).
  for (int i = t; i < (2*BUFB)/16; i += 256) ((f32x4*)lds)[i] = (f32x4){0.f,0.f,0.f,0.f};
  __syncthreads();

  if (ALH){
    const unsigned short* ap = alh + base;
    for (int idx = t; idx < 400; idx += 256){
      const int s = idx/50, n = idx - (idx/50)*50;
      const unsigned short* pp = ap + s*300 + n*6;
      const int r0 = s*8 + 2;
      #pragma unroll
      for (int y=0; y<6; ++y)
        *(unsigned short*)(lds + swz(r0 + y, n*2)) = pp[y];
    }
  } else {
    for (int idx = t; idx < 2400; idx += 256){
      const float v = io[base + idx];
      const int s = idx/300, rr = idx%300;
      const int ch = rr/6, y = rr%6;
      *(unsigned short*)(lds + swz(s*8 + y + 2, ch*2)) = f2h_bits(v);
    }
  }
  __syncthreads();

  if (ng == 0) conv_layer2<2,7,4,false>(lds, 0,    BUFB, wsU, 0,   0, b1, 100, m0, lane);
  else         conv_layer2<2,7,3,false>(lds, 0,    BUFB, wsU, 0,   4, b1, 100, m0, lane);
  __syncthreads();
  if (ng == 0) conv_layer2<4,7,4,false>(lds, BUFB, 0,    wsU, 42,  0, b2, 100, m0, lane);
  else         conv_layer2<4,7,3,false>(lds, BUFB, 0,    wsU, 42,  4, b2, 100, m0, lane);
  __syncthreads();
  if (ng == 0) conv_layer3_fused<4,4,2>(lds, 0, wsU, 126, 0, b3, Wl, bl, io, base, m0, lane);
  else         conv_layer3_fused<4,4,2>(lds, 0, wsU, 126, 2, b3, Wl, bl, io, base, m0, lane);
}

// ---------------- fallback conv (raw weights, VALU) — only if ws too small -----------
__device__ __forceinline__ float wraw(const float* __restrict__ W, int I, int i, int d, int o){
  return W[((o*I + i)*3 + d)*3 + 1];
}
template<int NS>
__device__ void conv_layer_valu(const float (* __restrict__ in)[100][8],
                                float (* __restrict__ outb)[100][8],
                                int I, const float* __restrict__ W,
                                const float* __restrict__ bias, int o, int s0)
{
  float acc[NS][6];
  const float b = bias[o];
  #pragma unroll
  for (int s=0;s<NS;s++)
    #pragma unroll
    for (int y=0;y<6;y++) acc[s][y]=b;
  for (int i=0;i<I;i++){
    const float w0 = wraw(W,I,i,0,o), w1 = wraw(W,I,i,1,o), w2 = wraw(W,I,i,2,o);
    #pragma unroll
    for (int s=0;s<NS;s++){
      const float4 r0 = *(const float4*)&in[s0+s][i][0];
      const float4 r1 = *(const float4*)&in[s0+s][i][4];
      acc[s][0] += w1*r0.x + w2*r0.y;
      acc[s][1] += w0*r0.x + w1*r0.y + w2*r0.z;
      acc[s][2] += w0*r0.y + w1*r0.z + w2*r0.w;
      acc[s][3] += w0*r0.z + w1*r0.w + w2*r1.x;
      acc[s][4] += w0*r0.w + w1*r1.x + w2*r1.y;
      acc[s][5] += w0*r1.x + w1*r1.y;
    }
  }
  #pragma unroll
  for (int s=0;s<NS;s++){
    float4 v0; float2 v1;
    v0.x = fmaxf(acc[s][0],0.f); v0.y = fmaxf(acc[s][1],0.f);
    v0.z = fmaxf(acc[s][2],0.f); v0.w = fmaxf(acc[s][3],0.f);
    v1.x = fmaxf(acc[s][4],0.f); v1.y = fmaxf(acc[s][5],0.f);
    *(float4*)&outb[s0+s][o][0] = v0;
    *(float2*)&outb[s0+s][o][4] = v1;
  }
}
__global__ __launch_bounds__(256,1) void conv_kernel_fb(
    float* __restrict__ io,
    const float* __restrict__ W1, const float* __restrict__ b1,
    const float* __restrict__ W2, const float* __restrict__ b2,
    const float* __restrict__ W3, const float* __restrict__ b3,
    const float* __restrict__ Wl, const float* __restrict__ bl)
{
  __shared__ float A[8][100][8];
  __shared__ float B[8][100][8];
  const int t = threadIdx.x;
  const size_t base = (size_t)blockIdx.x * 2400;
  for (int idx=t; idx<800; idx+=256){
    const int s = idx/100, ch = idx%100;
    A[s][ch][6]=0.f; A[s][ch][7]=0.f; B[s][ch][6]=0.f; B[s][ch][7]=0.f;
  }
  for (int idx=t; idx<2400; idx+=256){
    const float v = io[base + idx];
    const int s = idx/300, rr = idx%300;
    A[s][rr/6][rr%6] = v;
  }
  __syncthreads();
  const int w = t>>6, lane = t&63;
  { const int sh = w>>1, o = (w&1)*50 + lane;
    if (lane < 50) conv_layer_valu<4>(A, B, 50, W1, b1, o, sh*4); }
  __syncthreads();
  { const int sh = w>>1, o = (w&1)*50 + lane;
    if (lane < 50) conv_layer_valu<4>(B, A, 100, W2, b2, o, sh*4); }
  __syncthreads();
  { if (lane < 50) conv_layer_valu<2>(A, B, 100, W3, b3, lane, w*2); }
  __syncthreads();
  for (int idx=t; idx<2400; idx+=256){
    const int s = idx/300, rr = idx%300, n = rr/6, j = rr%6;
    const float4 r0 = *(const float4*)&B[s][n][0];
    const float2 r1 = *(const float2*)&B[s][n][4];
    io[base + idx] = bl[j] + Wl[j*6+0]*r0.x + Wl[j*6+1]*r0.y + Wl[j*6+2]*r0.z
                   + Wl[j*6+3]*r0.w + Wl[j*6+4]*r1.x + Wl[j*6+5]*r1.y;
  }
}

extern "C" void kernel_launch(void* const* d_in, const int* in_sizes, int n_in,
                              void* d_out, int out_size, void* d_ws, size_t ws_size,
                              hipStream_t stream)
{
  const float* X    = (const float*)d_in[1];
  const float* Wih  = (const float*)d_in[2];
  const float* Whh  = (const float*)d_in[3];
  const float* bih  = (const float*)d_in[4];
  const float* bhh  = (const float*)d_in[5];
  const float* Wf1  = (const float*)d_in[6];
  const float* bf1  = (const float*)d_in[7];
  const float* Wf2  = (const float*)d_in[8];
  const float* bf2  = (const float*)d_in[9];
  const float* Wf3  = (const float*)d_in[10];
  const float* bf3  = (const float*)d_in[11];
  const float* Wl   = (const float*)d_in[12];
  const float* bl   = (const float*)d_in[13];
  float* out = (float*)d_out;
  unsigned short* wsU = (unsigned short*)d_ws;

  const bool packed = (ws_size >= 174*512*sizeof(unsigned short));
  const bool bigws  = (ws_size >= (size_t)(ALH_OFF + 49152ull*300ull)*2ull);

  if (packed)
    hipLaunchKernelGGL(pack_frags, dim3(348), dim3(256), 0, stream,
                       Wf1, Wf2, Wf3, wsU);

  if (bigws && packed){
    unsigned short* alh = wsU + ALH_OFF;
    hipLaunchKernelGGL((lstm_scan2<true>), dim3((NCH/4)*5), dim3(128), 0, stream,
                       X, Wih, Whh, bih, bhh, nullptr, alh);
    hipLaunchKernelGGL((conv_mfma_kernel<true>), dim3(6144), dim3(256), 0, stream,
                       out, alh, wsU, bf1, bf2, bf3, Wl, bl);
  } else {
    hipLaunchKernelGGL((lstm_scan2<false>), dim3((NCH/4)*5), dim3(128), 0, stream,
                       X, Wih, Whh, bih, bhh, out, nullptr);
    if (packed)
      hipLaunchKernelGGL((conv_mfma_kernel<false>), dim3(6144), dim3(256), 0, stream,
                         out, nullptr, wsU, bf1, bf2, bf3, Wl, bl);
    else
      hipLaunchKernelGGL(conv_kernel_fb, dim3(6144), dim3(256), 0, stream,
                         out, Wf1, bf1, Wf2, bf2, Wf3, bf3, Wl, bl);
  }
}

// Round 23
// 205.301 us; speedup vs baseline: 1.0403x; 1.0403x over previous
//
#include <hip/hip_runtime.h>

#define NCH 1024          // LSTM chunks (divisible by 4)
#define CL 48             // steps per chunk
#define WM 16             // warm-up steps (validated: absmax unchanged)
// dual-stream, red 1.33 — R20 best-known LSTM config.

typedef _Float16 half8 __attribute__((ext_vector_type(8)));  // 8 f16 in 4 VGPRs
typedef float f32x4 __attribute__((ext_vector_type(4)));

#define ROWB 256          // bytes per LDS row (128 f16)
#define BUFB 16384        // 64 live rows (logical rows 1..64) * 256 B -> 32 KB total, 5 blocks/CU
#define ALH_OFF 131072    // ushort offset of f16 al inside ws (weights live below)

__device__ __forceinline__ unsigned short f2h_bits(float x){
  _Float16 h = (_Float16)x;
  return __builtin_bit_cast(unsigned short, h);
}

__device__ __forceinline__ float rcp_(float x){ return __builtin_amdgcn_rcpf(x); }
__device__ __forceinline__ float tanh_(float z){ return 1.f - 2.f*rcp_(1.f + __expf(2.f*z)); }

// Conv LDS addressing: logical rows 1..64 stored at physical (row-1)*ROWB.
// swzw: writer/stager form (row guaranteed in [1,64]).
// swzc: reader form with clamp — A-reads touch logical rows 0 and 65, whose products
// land ONLY in write-masked output rows (row R feeds crows {R-2,R-1,R}; p8(0)=0 and
// p8(63)=7 masked; MFMA output rows are independent), so clamped garbage is harmless.
__device__ __forceinline__ int swzw(int row, int b){
  return (row-1)*ROWB + (b ^ ((row&7)<<4));
}
__device__ __forceinline__ int swzc(int row, int b){
  int rc = row < 1 ? 1 : (row > 64 ? 64 : row);
  return (rc-1)*ROWB + (b ^ ((rc&7)<<4));
}

// ---------------- kernel 0: pack conv weights as f16 MFMA B-fragments ----------------
__global__ void pack_frags(const float* __restrict__ W1, const float* __restrict__ W2,
                           const float* __restrict__ W3, unsigned short* __restrict__ ws)
{
  int tid = blockIdx.x*256 + threadIdx.x;
  if (tid >= 174*512) return;
  int f = tid >> 9, e = tid & 511, l = e >> 3, j = e & 7;
  int d, ks, nt, I, O; const float* W;
  if (f < 42)      { int x = f;     int st = x/7;  nt = x%7; d = st/2; ks = st%2; I = 50;  O = 100; W = W1; }
  else if (f < 126){ int x = f-42;  int st = x/7;  nt = x%7; d = st/4; ks = st%4; I = 100; O = 100; W = W2; }
  else             { int x = f-126; int st = x/4;  nt = x%4; d = st/4; ks = st%4; I = 100; O = 50;  W = W3; }
  int k = ks*32 + ((l>>4)<<3) + j;
  int o = nt*16 + (l&15);
  float v = (k < I && o < O) ? W[((o*I + k)*3 + d)*3 + 1] : 0.f;
  ws[tid] = f2h_bits(v);
}

// ---------------- kernel 1: LSTM scan, dual-stream, 2 waves/WG (R20, unchanged) ------
template<bool F16>
__global__ __launch_bounds__(128,3) void lstm_scan2(
    const float* __restrict__ X, const float* __restrict__ Wih,
    const float* __restrict__ Whh, const float* __restrict__ bih,
    const float* __restrict__ bhh, float* __restrict__ al32,
    unsigned short* __restrict__ al16)
{
  const int l = threadIdx.x & 63;
  const int wv = threadIdx.x >> 6;
  const int blk = blockIdx.x;
  const int p4 = blk/5, w = blk - p4*5;
  const int q = l/6, j = l - q*6;
  const bool active = (q < 10);
  const int n = w*10 + (active ? q : 0);
  const int sbase = active ? q*6 : 0;

  const int c0 = p4*4 + 2*wv;           // this wave: chunks c0, c0+1
  const int sAb = c0*CL, sBb = sAb + CL;
  const int sALast = sAb + CL - 1, sBLast = sBb + CL - 1;

  float wi[4][12], wh[4][6], bb[4];
  #pragma unroll
  for (int g=0; g<4; ++g){
    const int r = g*6 + j;
    const float4 w0 = *(const float4*)(Wih + r*12);
    const float4 w1 = *(const float4*)(Wih + r*12 + 4);
    const float4 w2 = *(const float4*)(Wih + r*12 + 8);
    wi[g][0]=w0.x; wi[g][1]=w0.y; wi[g][2]=w0.z; wi[g][3]=w0.w;
    wi[g][4]=w1.x; wi[g][5]=w1.y; wi[g][6]=w1.z; wi[g][7]=w1.w;
    wi[g][8]=w2.x; wi[g][9]=w2.y; wi[g][10]=w2.z; wi[g][11]=w2.w;
    const float2 h0 = *(const float2*)(Whh + r*6);
    const float2 h1 = *(const float2*)(Whh + r*6 + 2);
    const float2 h2 = *(const float2*)(Whh + r*6 + 4);
    wh[g][0]=h0.x; wh[g][1]=h0.y; wh[g][2]=h1.x;
    wh[g][3]=h1.y; wh[g][4]=h2.x; wh[g][5]=h2.y;
    bb[g] = bih[r] + bhh[r];
  }

  float hA[6], hB[6], cA = 0.f, cB = 0.f;
  #pragma unroll
  for (int k=0;k<6;++k){ hA[k]=0.f; hB[k]=0.f; }

  const int sA0 = (c0==0) ? 0 : (sAb - WM);
  const int sB0 = sBb - WM;
  float4 xA0,xA1,xA2, xB0,xB1,xB2;
  { const float4* pa = (const float4*)(X + (size_t)sA0*600 + n*12); xA0=pa[0]; xA1=pa[1]; xA2=pa[2]; }
  { const float4* pb = (const float4*)(X + (size_t)sB0*600 + n*12); xB0=pb[0]; xB1=pb[1]; xB2=pb[2]; }

  auto step = [&](const float4& x0, const float4& x1, const float4& x2,
                  float* h, float& c) -> float {
    const float xr[12] = {x0.x,x0.y,x0.z,x0.w, x1.x,x1.y,x1.z,x1.w, x2.x,x2.y,x2.z,x2.w};
    float a0=bb[0], a1=bb[1], a2=bb[2], a3=bb[3];
    #pragma unroll
    for (int k=0;k<12;++k){ a0+=wi[0][k]*xr[k]; a1+=wi[1][k]*xr[k];
                            a2+=wi[2][k]*xr[k]; a3+=wi[3][k]*xr[k]; }
    #pragma unroll
    for (int k=0;k<6;++k){ a0+=wh[0][k]*h[k]; a1+=wh[1][k]*h[k];
                           a2+=wh[2][k]*h[k]; a3+=wh[3][k]*h[k]; }
    const float gi = rcp_(1.f + __expf(-a0));
    const float gf = rcp_(1.f + __expf(-a1));
    const float gg = 2.f*rcp_(1.f + __expf(-(a2+a2))) - 1.f;
    const float go = rcp_(1.f + __expf(-a3));
    c = gf*c + gi*gg;
    return tanh_(go * tanh_(c));
  };

  for (int i = -WM; i < CL; ++i){
    const int sA = sAb + i, sB = sBb + i;
    const bool doA = (sA >= 0);           // false only for c0==0 warm-up iters (uniform)
    float4 yA0,yA1,yA2, yB0,yB1,yB2;
    { const int sn = (sB < sBLast) ? sB+1 : sBLast;
      const float4* xq = (const float4*)(X + (size_t)sn*600 + n*12);
      yB0=xq[0]; yB1=xq[1]; yB2=xq[2]; }
    if (doA){
      const int sn = (sA < sALast) ? sA+1 : sALast;
      const float4* xq = (const float4*)(X + (size_t)sn*600 + n*12);
      yA0=xq[0]; yA1=xq[1]; yA2=xq[2];
    }

    float hnA = 0.f;
    if (doA) hnA = step(xA0,xA1,xA2, hA, cA);
    const float hnB = step(xB0,xB1,xB2, hB, cB);

    if (active && i >= 0){
      const size_t oA = (size_t)sA*300 + n*6 + j;
      const size_t oB = (size_t)sB*300 + n*6 + j;
      if (F16){ al16[oA] = f2h_bits(hnA); al16[oB] = f2h_bits(hnB); }
      else    { al32[oA] = hnA;           al32[oB] = hnB; }
    }
    #pragma unroll
    for (int k=0;k<6;++k){
      hA[k] = __shfl(hnA, sbase + k, 64);
      hB[k] = __shfl(hnB, sbase + k, 64);
    }
    if (doA){ xA0=yA0; xA1=yA1; xA2=yA2; }
    xB0=yB0; xB1=yB1; xB2=yB2;
  }
}

// ---------------- kernel 2: f16 MFMA conv x3, lean fused, 32 KB LDS ------------------
template<int KS, int NTT, int NTG, bool LAST>
__device__ __forceinline__ void conv_layer2(
    char* lds, int inOff, int outOff, const unsigned short* __restrict__ wsU,
    int fbase, int ntOff, const float* __restrict__ bias, int O, int m0, int lane)
{
  f32x4 acc[2][NTG];
  #pragma unroll
  for (int m=0;m<2;m++)
    #pragma unroll
    for (int n=0;n<NTG;n++) acc[m][n] = (f32x4){0.f,0.f,0.f,0.f};

  const int ar = m0 + (lane & 15);
  const int abyte_g = (lane>>4)<<4;
  const int laneb = lane << 3;

  half8 a0c = *(const half8*)(lds + inOff + swzc(ar, abyte_g));
  half8 a1c = *(const half8*)(lds + inOff + swzc(ar + 16, abyte_g));
  half8 bc[NTG];
  {
    const unsigned short* p0 = wsU + (size_t)(fbase + ntOff)*512 + laneb;
    #pragma unroll
    for (int n=0;n<NTG;n++) bc[n] = *(const half8*)(p0 + n*512);
  }

  #pragma unroll
  for (int st=0; st<3*KS; ++st){
    half8 a0n, a1n, bn[NTG];
    if (st+1 < 3*KS){
      const int dn = (st+1)/KS, ksn = (st+1)%KS;
      a0n = *(const half8*)(lds + inOff + swzc(ar + dn, ksn*64 + abyte_g));
      a1n = *(const half8*)(lds + inOff + swzc(ar + 16 + dn, ksn*64 + abyte_g));
      const unsigned short* pn = wsU + (size_t)(fbase + (st+1)*NTT + ntOff)*512 + laneb;
      #pragma unroll
      for (int n=0;n<NTG;n++) bn[n] = *(const half8*)(pn + n*512);
    }
    #pragma unroll
    for (int n=0;n<NTG;n++){
      acc[0][n] = __builtin_amdgcn_mfma_f32_16x16x32_f16(a0c, bc[n], acc[0][n], 0, 0, 0);
      acc[1][n] = __builtin_amdgcn_mfma_f32_16x16x32_f16(a1c, bc[n], acc[1][n], 0, 0, 0);
    }
    if (st+1 < 3*KS){
      a0c = a0n; a1c = a1n;
      #pragma unroll
      for (int n=0;n<NTG;n++) bc[n] = bn[n];
    }
  }

  const int colBase = lane & 15;
  #pragma unroll
  for (int m=0;m<2;m++){
    const int rbase = m0 + m*16 + ((lane>>4)<<2);
    #pragma unroll
    for (int n=0;n<NTG;n++){
      const int col = (ntOff + n)*16 + colBase;
      if (col < O){
        const float b = bias[col];
        #pragma unroll
        for (int r=0;r<4;r++){
          const int crow = rbase + r;
          const int p8 = crow & 7;
          if (p8 >= 1 && p8 <= 6){
            const float v = fmaxf(acc[m][n][r] + b, 0.f);
            const int srow = crow + 1;            // in [2,63]
            *(unsigned short*)(lds + outOff + swzw(srow, col*2)) = f2h_bits(v);
          }
        }
      }
    }
  }
}

// L3 with fused lean: relu(conv3)+b3 in regs; quad pairs via lane^16;
// lean = 18 reg-FMA + 6 shfl_xor + 3 float2 global stores.
template<int KS, int NTT, int NTG>
__device__ __forceinline__ void conv_layer3_fused(
    char* lds, int inOff, const unsigned short* __restrict__ wsU,
    int fbase, int ntOff, const float* __restrict__ b3,
    const float* __restrict__ Wl, const float* __restrict__ bl,
    float* __restrict__ io, size_t base, int m0, int lane)
{
  f32x4 acc[2][NTG];
  #pragma unroll
  for (int m=0;m<2;m++)
    #pragma unroll
    for (int n=0;n<NTG;n++) acc[m][n] = (f32x4){0.f,0.f,0.f,0.f};

  const int ar = m0 + (lane & 15);
  const int abyte_g = (lane>>4)<<4;
  const int laneb = lane << 3;

  half8 a0c = *(const half8*)(lds + inOff + swzc(ar, abyte_g));
  half8 a1c = *(const half8*)(lds + inOff + swzc(ar + 16, abyte_g));
  half8 bc[NTG];
  {
    const unsigned short* p0 = wsU + (size_t)(fbase + ntOff)*512 + laneb;
    #pragma unroll
    for (int n=0;n<NTG;n++) bc[n] = *(const half8*)(p0 + n*512);
  }

  #pragma unroll
  for (int st=0; st<3*KS; ++st){
    half8 a0n, a1n, bn[NTG];
    if (st+1 < 3*KS){
      const int dn = (st+1)/KS, ksn = (st+1)%KS;
      a0n = *(const half8*)(lds + inOff + swzc(ar + dn, ksn*64 + abyte_g));
      a1n = *(const half8*)(lds + inOff + swzc(ar + 16 + dn, ksn*64 + abyte_g));
      const unsigned short* pn = wsU + (size_t)(fbase + (st+1)*NTT + ntOff)*512 + laneb;
      #pragma unroll
      for (int n=0;n<NTG;n++) bn[n] = *(const half8*)(pn + n*512);
    }
    #pragma unroll
    for (int n=0;n<NTG;n++){
      acc[0][n] = __builtin_amdgcn_mfma_f32_16x16x32_f16(a0c, bc[n], acc[0][n], 0, 0, 0);
      acc[1][n] = __builtin_amdgcn_mfma_f32_16x16x32_f16(a1c, bc[n], acc[1][n], 0, 0, 0);
    }
    if (st+1 < 3*KS){
      a0c = a0n; a1c = a1n;
      #pragma unroll
      for (int n=0;n<NTG;n++) bc[n] = bn[n];
    }
  }

  const int colBase = lane & 15;
  const int qg = lane >> 4;
  const bool hiHalf = (qg & 1);
  #pragma unroll
  for (int m=0;m<2;m++){
    const int sIdx = (m0 + m*16 + qg*4) >> 3;
    #pragma unroll
    for (int n=0;n<NTG;n++){
      const int col = (ntOff + n)*16 + colBase;
      const bool valid = (col < 50);
      const float b = valid ? b3[col] : 0.f;
      float vv[4];
      #pragma unroll
      for (int r=0;r<4;r++) vv[r] = fmaxf(acc[m][n][r] + b, 0.f);
      float tot[6];
      #pragma unroll
      for (int j=0;j<6;j++){
        float pj;
        if (!hiHalf) pj = Wl[j*6+0]*vv[1] + Wl[j*6+1]*vv[2] + Wl[j*6+2]*vv[3];
        else         pj = Wl[j*6+3]*vv[0] + Wl[j*6+4]*vv[1] + Wl[j*6+5]*vv[2];
        tot[j] = pj + __shfl_xor(pj, 16, 64);
      }
      if (valid && !hiHalf){
        float* dst = io + base + (size_t)sIdx*300 + col*6;
        float2 p0 = {tot[0]+bl[0], tot[1]+bl[1]};
        float2 p1 = {tot[2]+bl[2], tot[3]+bl[3]};
        float2 p2 = {tot[4]+bl[4], tot[5]+bl[5]};
        *(float2*)(dst+0) = p0;
        *(float2*)(dst+2) = p1;
        *(float2*)(dst+4) = p2;
      }
    }
  }
}

template<bool ALH>
__global__ __launch_bounds__(256,5) void conv_mfma_kernel(
    float* __restrict__ io, const unsigned short* __restrict__ alh,
    const unsigned short* __restrict__ wsU,
    const float* __restrict__ b1, const float* __restrict__ b2, const float* __restrict__ b3,
    const float* __restrict__ Wl, const float* __restrict__ bl)
{
  __shared__ __align__(16) char lds[2*BUFB];     // 32 KB -> 5 blocks/CU
  const int t = threadIdx.x;
  const int lane = t & 63, w = t >> 6;
  const int mg = w >> 1, ng = w & 1;
  const int m0 = mg*32;
  const size_t base = (size_t)blockIdx.x * 2400;

  // Zero BOTH buffers fully (R6 lesson: LDS NaN in the K-pad is laundered to wrong
  // finite values by fmaxf(NaN,0)=0 -> silent corruption).
  for (int i = t; i < (2*BUFB)/16; i += 256) ((f32x4*)lds)[i] = (f32x4){0.f,0.f,0.f,0.f};
  __syncthreads();

  if (ALH){
    const unsigned short* ap = alh + base;
    for (int idx = t; idx < 400; idx += 256){
      const int s = idx/50, n = idx - (idx/50)*50;
      const unsigned short* pp = ap + s*300 + n*6;
      const int r0 = s*8 + 2;
      #pragma unroll
      for (int y=0; y<6; ++y)
        *(unsigned short*)(lds + swzw(r0 + y, n*2)) = pp[y];
    }
  } else {
    for (int idx = t; idx < 2400; idx += 256){
      const float v = io[base + idx];
      const int s = idx/300, rr = idx%300;
      const int ch = rr/6, y = rr%6;
      *(unsigned short*)(lds + swzw(s*8 + y + 2, ch*2)) = f2h_bits(v);
    }
  }
  __syncthreads();

  if (ng == 0) conv_layer2<2,7,4,false>(lds, 0,    BUFB, wsU, 0,   0, b1, 100, m0, lane);
  else         conv_layer2<2,7,3,false>(lds, 0,    BUFB, wsU, 0,   4, b1, 100, m0, lane);
  __syncthreads();
  if (ng == 0) conv_layer2<4,7,4,false>(lds, BUFB, 0,    wsU, 42,  0, b2, 100, m0, lane);
  else         conv_layer2<4,7,3,false>(lds, BUFB, 0,    wsU, 42,  4, b2, 100, m0, lane);
  __syncthreads();
  if (ng == 0) conv_layer3_fused<4,4,2>(lds, 0, wsU, 126, 0, b3, Wl, bl, io, base, m0, lane);
  else         conv_layer3_fused<4,4,2>(lds, 0, wsU, 126, 2, b3, Wl, bl, io, base, m0, lane);
}

// ---------------- fallback conv (raw weights, VALU) — only if ws too small -----------
__device__ __forceinline__ float wraw(const float* __restrict__ W, int I, int i, int d, int o){
  return W[((o*I + i)*3 + d)*3 + 1];
}
template<int NS>
__device__ void conv_layer_valu(const float (* __restrict__ in)[100][8],
                                float (* __restrict__ outb)[100][8],
                                int I, const float* __restrict__ W,
                                const float* __restrict__ bias, int o, int s0)
{
  float acc[NS][6];
  const float b = bias[o];
  #pragma unroll
  for (int s=0;s<NS;s++)
    #pragma unroll
    for (int y=0;y<6;y++) acc[s][y]=b;
  for (int i=0;i<I;i++){
    const float w0 = wraw(W,I,i,0,o), w1 = wraw(W,I,i,1,o), w2 = wraw(W,I,i,2,o);
    #pragma unroll
    for (int s=0;s<NS;s++){
      const float4 r0 = *(const float4*)&in[s0+s][i][0];
      const float4 r1 = *(const float4*)&in[s0+s][i][4];
      acc[s][0] += w1*r0.x + w2*r0.y;
      acc[s][1] += w0*r0.x + w1*r0.y + w2*r0.z;
      acc[s][2] += w0*r0.y + w1*r0.z + w2*r0.w;
      acc[s][3] += w0*r0.z + w1*r0.w + w2*r1.x;
      acc[s][4] += w0*r0.w + w1*r1.x + w2*r1.y;
      acc[s][5] += w0*r1.x + w1*r1.y;
    }
  }
  #pragma unroll
  for (int s=0;s<NS;s++){
    float4 v0; float2 v1;
    v0.x = fmaxf(acc[s][0],0.f); v0.y = fmaxf(acc[s][1],0.f);
    v0.z = fmaxf(acc[s][2],0.f); v0.w = fmaxf(acc[s][3],0.f);
    v1.x = fmaxf(acc[s][4],0.f); v1.y = fmaxf(acc[s][5],0.f);
    *(float4*)&outb[s0+s][o][0] = v0;
    *(float2*)&outb[s0+s][o][4] = v1;
  }
}
__global__ __launch_bounds__(256,1) void conv_kernel_fb(
    float* __restrict__ io,
    const float* __restrict__ W1, const float* __restrict__ b1,
    const float* __restrict__ W2, const float* __restrict__ b2,
    const float* __restrict__ W3, const float* __restrict__ b3,
    const float* __restrict__ Wl, const float* __restrict__ bl)
{
  __shared__ float A[8][100][8];
  __shared__ float B[8][100][8];
  const int t = threadIdx.x;
  const size_t base = (size_t)blockIdx.x * 2400;
  for (int idx=t; idx<800; idx+=256){
    const int s = idx/100, ch = idx%100;
    A[s][ch][6]=0.f; A[s][ch][7]=0.f; B[s][ch][6]=0.f; B[s][ch][7]=0.f;
  }
  for (int idx=t; idx<2400; idx+=256){
    const float v = io[base + idx];
    const int s = idx/300, rr = idx%300;
    A[s][rr/6][rr%6] = v;
  }
  __syncthreads();
  const int w = t>>6, lane = t&63;
  { const int sh = w>>1, o = (w&1)*50 + lane;
    if (lane < 50) conv_layer_valu<4>(A, B, 50, W1, b1, o, sh*4); }
  __syncthreads();
  { const int sh = w>>1, o = (w&1)*50 + lane;
    if (lane < 50) conv_layer_valu<4>(B, A, 100, W2, b2, o, sh*4); }
  __syncthreads();
  { if (lane < 50) conv_layer_valu<2>(A, B, 100, W3, b3, lane, w*2); }
  __syncthreads();
  for (int idx=t; idx<2400; idx+=256){
    const int s = idx/300, rr = idx%300, n = rr/6, j = rr%6;
    const float4 r0 = *(const float4*)&B[s][n][0];
    const float2 r1 = *(const float2*)&B[s][n][4];
    io[base + idx] = bl[j] + Wl[j*6+0]*r0.x + Wl[j*6+1]*r0.y + Wl[j*6+2]*r0.z
                   + Wl[j*6+3]*r0.w + Wl[j*6+4]*r1.x + Wl[j*6+5]*r1.y;
  }
}

extern "C" void kernel_launch(void* const* d_in, const int* in_sizes, int n_in,
                              void* d_out, int out_size, void* d_ws, size_t ws_size,
                              hipStream_t stream)
{
  const float* X    = (const float*)d_in[1];
  const float* Wih  = (const float*)d_in[2];
  const float* Whh  = (const float*)d_in[3];
  const float* bih  = (const float*)d_in[4];
  const float* bhh  = (const float*)d_in[5];
  const float* Wf1  = (const float*)d_in[6];
  const float* bf1  = (const float*)d_in[7];
  const float* Wf2  = (const float*)d_in[8];
  const float* bf2  = (const float*)d_in[9];
  const float* Wf3  = (const float*)d_in[10];
  const float* bf3  = (const float*)d_in[11];
  const float* Wl   = (const float*)d_in[12];
  const float* bl   = (const float*)d_in[13];
  float* out = (float*)d_out;
  unsigned short* wsU = (unsigned short*)d_ws;

  const bool packed = (ws_size >= 174*512*sizeof(unsigned short));
  const bool bigws  = (ws_size >= (size_t)(ALH_OFF + 49152ull*300ull)*2ull);

  if (packed)
    hipLaunchKernelGGL(pack_frags, dim3(348), dim3(256), 0, stream,
                       Wf1, Wf2, Wf3, wsU);

  if (bigws && packed){
    unsigned short* alh = wsU + ALH_OFF;
    hipLaunchKernelGGL((lstm_scan2<true>), dim3((NCH/4)*5), dim3(128), 0, stream,
                       X, Wih, Whh, bih, bhh, nullptr, alh);
    hipLaunchKernelGGL((conv_mfma_kernel<true>), dim3(6144), dim3(256), 0, stream,
                       out, alh, wsU, bf1, bf2, bf3, Wl, bl);
  } else {
    hipLaunchKernelGGL((lstm_scan2<false>), dim3((NCH/4)*5), dim3(128), 0, stream,
                       X, Wih, Whh, bih, bhh, out, nullptr);
    if (packed)
      hipLaunchKernelGGL((conv_mfma_kernel<false>), dim3(6144), dim3(256), 0, stream,
                         out, nullptr, wsU, bf1, bf2, bf3, Wl, bl);
    else
      hipLaunchKernelGGL(conv_kernel_fb, dim3(6144), dim3(256), 0, stream,
                         out, Wf1, bf1, Wf2, bf2, Wf3, bf3, Wl, bl);
  }
}